// Round 1
// baseline (2186.204 us; speedup 1.0000x reference)
//
#include <hip/hip_runtime.h>

typedef __bf16 bf16x8 __attribute__((ext_vector_type(8)));
typedef float f32x4 __attribute__((ext_vector_type(4)));
typedef unsigned short u16;
typedef unsigned int u32;

#define NF_ 133
#define EF_ 14
#define HD 300
#define KH 320   // padded K for h GEMMs (10 ksteps of 32)
#define K0 160   // padded K for h0 GEMM (133+14 -> 160)
#define K2 448   // padded K for node GEMM (133+300 -> 448)
#define NT 19    // n tiles of 16 covering 300 (pad 304)

__device__ __forceinline__ u16 f2bf(float f) {
    union { float f; u32 u; } v; v.f = f;
    u32 r = v.u + 0x7fffu + ((v.u >> 16) & 1u);
    return (u16)(r >> 16);
}
__device__ __forceinline__ float bf2f(u16 h) {
    union { u32 u; float f; } v; v.u = ((u32)h) << 16;
    return v.f;
}

// ---------- prep: W[K][N] fp32 -> Wt[NP][KP] bf16 (N-major, zero padded) ----------
__global__ void prep_w(const float* __restrict__ W, u16* __restrict__ Wt,
                       int K, int N, int KP, int NP) {
    int idx = blockIdx.x * 256 + threadIdx.x;
    if (idx >= NP * KP) return;
    int n = idx / KP, k = idx - n * KP;
    float val = (k < K && n < N) ? W[k * N + n] : 0.f;
    Wt[idx] = f2bf(val);
}

// ---------- prep: globals -> Ar1 cols [300,512) ----------
__global__ void prep_glob(const float* __restrict__ glob, u16* __restrict__ Ar1) {
    int idx = blockIdx.x * 256 + threadIdx.x;
    if (idx >= 4096 * 212) return;
    int g = idx / 212, c = 300 + (idx - g * 212);
    float val = (c < 500) ? glob[g * 200 + (c - 300)] : 0.f;
    Ar1[g * 512 + c] = f2bf(val);
}

// ---------- mega kernel: one block per graph ----------
// LDS interleaved layout for MFMA-A buffers: elem(e,c) = (c/8)*(ROWS*8) + e*8 + (c%8)
__global__ __launch_bounds__(256, 1) void gnn_mega(
    const float* __restrict__ vf, const float* __restrict__ ef,
    const int* __restrict__ src, const int* __restrict__ dst,
    const u16* __restrict__ WiT, const u16* __restrict__ WmT, const u16* __restrict__ WaT,
    const float* __restrict__ bi, const float* __restrict__ bm, const float* __restrict__ ba,
    u16* __restrict__ Ar1)
{
    __shared__ u16 sh[64 * KH];     // h, ROWS=64 interleave, 40960 B
    __shared__ u16 sm[64 * KH];     // m_e / A0 / A2,          40960 B
    __shared__ float sacc[32 * 322];// acc (pitch 322) / hvf,  41216 B
    __shared__ int s_src[64], s_dst[64];
    __shared__ unsigned char s_nbr[32][24], s_snbr[32][24];
    __shared__ int s_deg[32], s_sdeg[32];

    const int g = blockIdx.x;
    const int tid = threadIdx.x;
    const int wave = tid >> 6;
    const int lane = tid & 63;
    const int lm = lane & 15;
    const int q = lane >> 4;

    if (tid < 64) {
        s_src[tid] = src[g * 64 + tid] - g * 32;
        s_dst[tid] = dst[g * 64 + tid] - g * 32;
    }
    __syncthreads();

    // adjacency lists (in-edges by dst for acc; out-edges by src for m_v)
    if (tid < 32) {
        int d = 0, sd = 0;
        for (int k = 0; k < 64; ++k) {
            if (s_dst[k] == tid && d < 24) s_nbr[tid][d++] = (unsigned char)k;
            if (s_src[k] == tid && sd < 24) s_snbr[tid][sd++] = (unsigned char)k;
        }
        s_deg[tid] = d; s_sdeg[tid] = sd;
    }
    // zero h (pads cols 300..319 must stay 0 forever)
    {
        u32* p = (u32*)sh;
        for (int i = tid; i < 64 * KH / 2; i += 256) p[i] = 0u;
    }
    // build A0 = [vv[src[e]] | ee | 0] in sm, interleaved ROWS=64, K0=160
    for (int idx = tid; idx < 64 * K0; idx += 256) {
        int ed = idx & 63, c = idx >> 6;
        float val = 0.f;
        if (c < NF_) val = vf[(g * 32 + s_src[ed]) * (NF_ + 1) + c];
        else if (c < NF_ + EF_) val = ef[(g * 64 + ed) * (EF_ + 1) + (c - NF_)];
        sm[((c >> 3) << 9) + (ed << 3) + (c & 7)] = f2bf(val);
    }
    __syncthreads();

    // ---------------- h0 GEMM: (64 x 160) @ WiT -> h0 (64 x 300) ----------------
    f32x4 h0r[5][4];
    {
        f32x4 acc[5][4];
        #pragma unroll
        for (int t = 0; t < 5; ++t)
            #pragma unroll
            for (int mt = 0; mt < 4; ++mt) acc[t][mt] = (f32x4){0.f, 0.f, 0.f, 0.f};
        #pragma unroll
        for (int ks = 0; ks < 5; ++ks) {
            bf16x8 af[4];
            #pragma unroll
            for (int mt = 0; mt < 4; ++mt)
                af[mt] = *(const bf16x8*)&sm[((ks * 4 + q) << 9) + ((mt * 16 + lm) << 3)];
            #pragma unroll
            for (int t = 0; t < 5; ++t) {
                int j = 4 * t + wave;
                if (j < NT) {
                    bf16x8 bfr = *(const bf16x8*)&WiT[(j * 16 + lm) * K0 + ks * 32 + q * 8];
                    #pragma unroll
                    for (int mt = 0; mt < 4; ++mt)
                        acc[t][mt] = __builtin_amdgcn_mfma_f32_16x16x32_bf16(af[mt], bfr, acc[t][mt], 0, 0, 0);
                }
            }
        }
        #pragma unroll
        for (int t = 0; t < 5; ++t) {
            int j = 4 * t + wave;
            int n = j * 16 + lm;
            bool ok = (j < NT) && (n < HD);
            float bv = ok ? bi[n] : 0.f;
            int base = ok ? (((n >> 3) << 9) + (n & 7)) : 0;
            #pragma unroll
            for (int mt = 0; mt < 4; ++mt) {
                #pragma unroll
                for (int r = 0; r < 4; ++r) {
                    float hv = acc[t][mt][r] + bv;
                    hv = hv > 0.f ? hv : 0.f;
                    h0r[t][mt][r] = hv;
                    if (ok) sh[base + ((mt * 16 + q * 4 + r) << 3)] = f2bf(hv);
                }
            }
        }
    }
    __syncthreads();

    // preload bm per tile
    float bmv[5];
    #pragma unroll
    for (int t = 0; t < 5; ++t) {
        int j = 4 * t + wave; int n = j * 16 + lm;
        bmv[t] = (j < NT && n < HD) ? bm[n] : 0.f;
    }

    const u32* shu = (const u32*)sh;
    u32* smu = (u32*)sm;

    for (int layer = 0; layer < 3; ++layer) {
        // ---- acc[n][c] = sum_{dst==n} h[e][c], f32, full 320 width ----
        {
            int n = tid >> 3, d0 = tid & 7;
            int dg = s_deg[n];
            #pragma unroll
            for (int i = 0; i < 20; ++i) {
                int d = d0 + (i << 3);                 // dword col, c = 2d
                float a0 = 0.f, a1 = 0.f;
                for (int k = 0; k < dg; ++k) {
                    int eidx = s_nbr[n][k];
                    u32 h2 = shu[((d >> 2) << 8) + (eidx << 2) + (d & 3)];
                    a0 += bf2f((u16)(h2 & 0xffffu));
                    a1 += bf2f((u16)(h2 >> 16));
                }
                *(float2*)&sacc[n * 322 + 2 * d] = make_float2(a0, a1);
            }
        }
        __syncthreads();
        // ---- m[e][c] = acc[src[e]][c] - h[e^1][c] -> bf16 into sm ----
        {
            int ed = tid >> 2, d0 = tid & 3;
            int sl = s_src[ed];
            #pragma unroll
            for (int i = 0; i < 40; ++i) {
                int d = d0 + (i << 2);
                float2 a = *(const float2*)&sacc[sl * 322 + 2 * d];
                u32 h2 = shu[((d >> 2) << 8) + ((ed ^ 1) << 2) + (d & 3)];
                float m0 = a.x - bf2f((u16)(h2 & 0xffffu));
                float m1 = a.y - bf2f((u16)(h2 >> 16));
                smu[((d >> 2) << 8) + (ed << 2) + (d & 3)] = (u32)f2bf(m0) | ((u32)f2bf(m1) << 16);
            }
        }
        __syncthreads();
        // ---- h = relu(h0 + m @ Wm + bm) ----
        {
            f32x4 acc[5][4];
            #pragma unroll
            for (int t = 0; t < 5; ++t)
                #pragma unroll
                for (int mt = 0; mt < 4; ++mt) acc[t][mt] = (f32x4){0.f, 0.f, 0.f, 0.f};
            #pragma unroll
            for (int ks = 0; ks < 10; ++ks) {
                bf16x8 af[4];
                #pragma unroll
                for (int mt = 0; mt < 4; ++mt)
                    af[mt] = *(const bf16x8*)&sm[((ks * 4 + q) << 9) + ((mt * 16 + lm) << 3)];
                #pragma unroll
                for (int t = 0; t < 5; ++t) {
                    int j = 4 * t + wave;
                    if (j < NT) {
                        bf16x8 bfr = *(const bf16x8*)&WmT[(j * 16 + lm) * KH + ks * 32 + q * 8];
                        #pragma unroll
                        for (int mt = 0; mt < 4; ++mt)
                            acc[t][mt] = __builtin_amdgcn_mfma_f32_16x16x32_bf16(af[mt], bfr, acc[t][mt], 0, 0, 0);
                    }
                }
            }
            #pragma unroll
            for (int t = 0; t < 5; ++t) {
                int j = 4 * t + wave;
                int n = j * 16 + lm;
                bool ok = (j < NT) && (n < HD);
                int base = ok ? (((n >> 3) << 9) + (n & 7)) : 0;
                #pragma unroll
                for (int mt = 0; mt < 4; ++mt) {
                    #pragma unroll
                    for (int r = 0; r < 4; ++r) {
                        float hv = h0r[t][mt][r] + acc[t][mt][r] + bmv[t];
                        hv = hv > 0.f ? hv : 0.f;
                        if (ok) sh[base + ((mt * 16 + q * 4 + r) << 3)] = f2bf(hv);
                    }
                }
            }
        }
        __syncthreads();
    }

    // ---- A2 = [vv | m_v | 0] (32 x 448), interleaved ROWS=32, into sm ----
    for (int idx = tid; idx < 32 * K2; idx += 256) {
        int n = idx & 31, c = idx >> 5;
        float val = 0.f;
        if (c < NF_) val = vf[(g * 32 + n) * (NF_ + 1) + c];
        else if (c < NF_ + HD) {
            int hc = c - NF_;
            int sd = s_sdeg[n];
            float s = 0.f;
            for (int k = 0; k < sd; ++k) {
                int eidx = s_snbr[n][k];
                s += bf2f(sh[((hc >> 3) << 9) + (eidx << 3) + (hc & 7)]);
            }
            val = s;
        }
        sm[((c >> 3) << 8) + (n << 3) + (c & 7)] = f2bf(val);
    }
    __syncthreads();

    // ---- h_v = relu(A2 @ Wa + ba), then mean over 32 nodes -> Ar1[g][0:300] ----
    {
        f32x4 acc[5][2];
        #pragma unroll
        for (int t = 0; t < 5; ++t)
            #pragma unroll
            for (int mt = 0; mt < 2; ++mt) acc[t][mt] = (f32x4){0.f, 0.f, 0.f, 0.f};
        #pragma unroll
        for (int ks = 0; ks < 14; ++ks) {
            bf16x8 af[2];
            #pragma unroll
            for (int mt = 0; mt < 2; ++mt)
                af[mt] = *(const bf16x8*)&sm[((ks * 4 + q) << 8) + ((mt * 16 + lm) << 3)];
            #pragma unroll
            for (int t = 0; t < 5; ++t) {
                int j = 4 * t + wave;
                if (j < NT) {
                    bf16x8 bfr = *(const bf16x8*)&WaT[(j * 16 + lm) * K2 + ks * 32 + q * 8];
                    #pragma unroll
                    for (int mt = 0; mt < 2; ++mt)
                        acc[t][mt] = __builtin_amdgcn_mfma_f32_16x16x32_bf16(af[mt], bfr, acc[t][mt], 0, 0, 0);
                }
            }
        }
        #pragma unroll
        for (int t = 0; t < 5; ++t) {
            int j = 4 * t + wave;
            int n = j * 16 + lm;
            bool ok = (j < NT) && (n < HD);
            float bav = ok ? ba[n] : 0.f;
            #pragma unroll
            for (int mt = 0; mt < 2; ++mt) {
                #pragma unroll
                for (int r = 0; r < 4; ++r) {
                    float hv = acc[t][mt][r] + bav;
                    hv = hv > 0.f ? hv : 0.f;
                    if (ok) sacc[(mt * 16 + q * 4 + r) * 304 + n] = hv;  // hvf reuse of sacc
                }
            }
        }
    }
    __syncthreads();
    for (int c = tid; c < HD; c += 256) {
        float s = 0.f;
        #pragma unroll
        for (int n = 0; n < 32; ++n) s += sacc[n * 304 + c];
        Ar1[g * 512 + c] = f2bf(s * 0.03125f);
    }
}

// ---------- generic LDS-free readout GEMM: C = [relu](A @ Bt^T + bias) ----------
template<int RELU, int OUTBF16>
__global__ __launch_bounds__(256, 4) void gemm_ro(
    const u16* __restrict__ A, const u16* __restrict__ Bt, const float* __restrict__ bias,
    const int KP, const int Nreal, const int outPitch, void* __restrict__ outp, const int nsteps)
{
    const int tid = threadIdx.x;
    const int wv = tid >> 6, lane = tid & 63, lm = lane & 15, q = lane >> 4;
    const int row0 = blockIdx.x * 64;
    const int col = blockIdx.y * 64 + wv * 16 + lm;
    f32x4 acc[4];
    #pragma unroll
    for (int mt = 0; mt < 4; ++mt) acc[mt] = (f32x4){0.f, 0.f, 0.f, 0.f};
    const u16* bp = Bt + col * KP + q * 8;
    const u16* ap = A + (row0 + lm) * KP + q * 8;
    for (int ks = 0; ks < nsteps; ++ks) {
        bf16x8 bfr = *(const bf16x8*)(bp + ks * 32);
        #pragma unroll
        for (int mt = 0; mt < 4; ++mt) {
            bf16x8 afr = *(const bf16x8*)(ap + mt * 16 * KP + ks * 32);
            acc[mt] = __builtin_amdgcn_mfma_f32_16x16x32_bf16(afr, bfr, acc[mt], 0, 0, 0);
        }
    }
    const float bv = (col < Nreal) ? bias[col] : 0.f;
    #pragma unroll
    for (int mt = 0; mt < 4; ++mt) {
        #pragma unroll
        for (int r = 0; r < 4; ++r) {
            int row = row0 + mt * 16 + q * 4 + r;
            float val = acc[mt][r] + bv;
            if (RELU) val = val > 0.f ? val : 0.f;
            if (OUTBF16) {
                ((u16*)outp)[row * outPitch + col] = (col < Nreal) ? f2bf(val) : (u16)0;
            } else {
                if (col < Nreal) ((float*)outp)[row * outPitch + col] = val;
            }
        }
    }
}

extern "C" void kernel_launch(void* const* d_in, const int* in_sizes, int n_in,
                              void* d_out, int out_size, void* d_ws, size_t ws_size,
                              hipStream_t stream) {
    (void)in_sizes; (void)n_in; (void)out_size; (void)ws_size;
    const float* v   = (const float*)d_in[0];
    const float* e   = (const float*)d_in[1];
    const float* glb = (const float*)d_in[2];
    const float* Wi  = (const float*)d_in[3];
    const float* bi  = (const float*)d_in[4];
    const float* Wm  = (const float*)d_in[5];
    const float* bm  = (const float*)d_in[6];
    const float* Wa  = (const float*)d_in[7];
    const float* ba  = (const float*)d_in[8];
    const float* Wr1 = (const float*)d_in[9];
    const float* br1 = (const float*)d_in[10];
    const float* Wr2 = (const float*)d_in[11];
    const float* br2 = (const float*)d_in[12];
    const float* Wr3 = (const float*)d_in[13];
    const float* br3 = (const float*)d_in[14];
    const int* src = (const int*)d_in[15];
    const int* dst = (const int*)d_in[16];

    char* ws = (char*)d_ws;
    u16* WiT  = (u16*)(ws + 0);            // 304*160*2  =   97280
    u16* WmT  = (u16*)(ws + 97280);        // 304*320*2  =  194560
    u16* WaT  = (u16*)(ws + 291840);       // 304*448*2  =  272384
    u16* Wr1T = (u16*)(ws + 564224);       // 576*512*2  =  589824
    u16* Wr2T = (u16*)(ws + 1154048);      // 384*576*2  =  442368
    u16* Wr3T = (u16*)(ws + 1596416);      //  64*384*2  =   49152
    u16* Ar1  = (u16*)(ws + 1645568);      // 4096*512*2 = 4194304
    u16* Ar2  = (u16*)(ws + 5839872);      // 4096*576*2 = 4718592
    u16* Ar3  = (u16*)(ws + 10558464);     // 4096*384*2 = 3145728

    prep_w<<<190,  256, 0, stream>>>(Wi,  WiT,  147, 300, 160, 304);
    prep_w<<<380,  256, 0, stream>>>(Wm,  WmT,  300, 300, 320, 304);
    prep_w<<<532,  256, 0, stream>>>(Wa,  WaT,  433, 300, 448, 304);
    prep_w<<<1152, 256, 0, stream>>>(Wr1, Wr1T, 500, 550, 512, 576);
    prep_w<<<864,  256, 0, stream>>>(Wr2, Wr2T, 550, 378, 576, 384);
    prep_w<<<96,   256, 0, stream>>>(Wr3, Wr3T, 378, 12,  384, 64);
    prep_glob<<<3392, 256, 0, stream>>>(glb, Ar1);

    gnn_mega<<<4096, 256, 0, stream>>>(v, e, src, dst, WiT, WmT, WaT, bi, bm, ba, Ar1);

    gemm_ro<1, 1><<<dim3(64, 9), 256, 0, stream>>>(Ar1, Wr1T, br1, 512, 550, 576, Ar2, 16);
    gemm_ro<1, 1><<<dim3(64, 6), 256, 0, stream>>>(Ar2, Wr2T, br2, 576, 378, 384, Ar3, 18);
    gemm_ro<0, 0><<<dim3(64, 1), 256, 0, stream>>>(Ar3, Wr3T, br3, 384, 12, 12, d_out, 12);
}

// Round 2
// 935.652 us; speedup vs baseline: 2.3366x; 2.3366x over previous
//
#include <hip/hip_runtime.h>

typedef __bf16 bf16x8 __attribute__((ext_vector_type(8)));
typedef float f32x4 __attribute__((ext_vector_type(4)));
typedef unsigned short u16;
typedef unsigned int u32;
typedef unsigned long long u64;

#define NF_ 133
#define EF_ 14
#define HD 300
#define KH 320   // padded K for h GEMMs (10 ksteps of 32)
#define K0 160   // padded K for h0 GEMM (133+14 -> 160)
#define K2 448   // padded K for node GEMM (133+300 -> 448)
#define NT 19    // n tiles of 16 covering 300 (pad 304)

__device__ __forceinline__ u16 f2bf(float f) {
    union { float f; u32 u; } v; v.f = f;
    u32 r = v.u + 0x7fffu + ((v.u >> 16) & 1u);
    return (u16)(r >> 16);
}

// ---------- prep: W[K][N] fp32 -> Wt[NP][KP] bf16 (N-major, zero padded) ----------
__global__ void prep_w(const float* __restrict__ W, u16* __restrict__ Wt,
                       int K, int N, int KP, int NP) {
    int idx = blockIdx.x * 256 + threadIdx.x;
    if (idx >= NP * KP) return;
    int n = idx / KP, k = idx - n * KP;
    float val = (k < K && n < N) ? W[k * N + n] : 0.f;
    Wt[idx] = f2bf(val);
}

// ---------- prep: globals -> Ar1 cols [300,512) ----------
__global__ void prep_glob(const float* __restrict__ glob, u16* __restrict__ Ar1) {
    int idx = blockIdx.x * 256 + threadIdx.x;
    if (idx >= 4096 * 212) return;
    int g = idx / 212, c = 300 + (idx - g * 212);
    float val = (c < 500) ? glob[g * 200 + (c - 300)] : 0.f;
    Ar1[g * 512 + c] = f2bf(val);
}

// ---------- mega kernel: one block (512 thr) per graph ----------
// A-operand LDS layout (rows R, K cols): elem(r,c) = (c/8)*(R*8) + r*8 + (c%8)
// B-operand (hT) layout: elem(c,k) = (k/8)*(320*8) + c*8 + (k%8)
__global__ __launch_bounds__(512, 1) void gnn_mega(
    const float* __restrict__ vf, const float* __restrict__ ef,
    const int* __restrict__ src, const int* __restrict__ dst,
    const u16* __restrict__ WiT, const u16* __restrict__ WmT, const u16* __restrict__ WaT,
    const float* __restrict__ bi, const float* __restrict__ bm, const float* __restrict__ ba,
    u16* __restrict__ Ar1)
{
    __shared__ u16 sm[64 * KH];    // A0 / m / A2 (A-layout), 40960 B
    __shared__ u16 shT[8 * 2560];  // h transposed (B-layout), 40960 B
    __shared__ u16 sAe[8 * 512];   // A_e 64x64 (A-layout R=64), 8192 B
    __shared__ u16 sSo[8 * 256];   // S_out 32x64 (A-layout R=32), 4096 B
    __shared__ int s_src[64], s_dst[64];

    const int g = blockIdx.x;
    const int tid = threadIdx.x;
    const int wave = tid >> 6;
    const int lane = tid & 63;
    const int lm = lane & 15;
    const int q = lane >> 4;

    if (tid < 64) {
        s_src[tid] = src[g * 64 + tid] - g * 32;
        s_dst[tid] = dst[g * 64 + tid] - g * 32;
    }
    __syncthreads();

    // zero hT fully (pads c>=300 must stay 0); zero sm tail chunks (c 304..319)
    for (int i = tid; i < 10240; i += 512) ((u32*)shT)[i] = 0u;
    if (tid < 512) ((u32*)sm)[9728 + tid] = 0u;

    // build A_e[e][k] = (dst[k]==src[e] && k!=(e^1)) in A-layout
    for (int idx = tid; idx < 4096; idx += 512) {
        int e = idx >> 6, k = idx & 63;
        u16 v = (s_dst[k] == s_src[e] && k != (e ^ 1)) ? (u16)0x3F80 : (u16)0;
        sAe[((k >> 3) << 9) + (e << 3) + (k & 7)] = v;
    }
    // build S_out[n][k] = (src[k]==n)
    for (int idx = tid; idx < 2048; idx += 512) {
        int n = idx >> 6, k = idx & 63;
        sSo[((k >> 3) << 8) + (n << 3) + (k & 7)] = (s_src[k] == n) ? (u16)0x3F80 : (u16)0;
    }
    // build A0 = [vv[src[e]] | ee | 0] (64 x 160), c-fastest for coalescing
    for (int idx = tid; idx < 64 * K0; idx += 512) {
        int ed = idx / K0, c = idx - ed * K0;
        float val = 0.f;
        if (c < NF_) val = vf[(size_t)(g * 32 + s_src[ed]) * (NF_ + 1) + c];
        else if (c < NF_ + EF_) val = ef[(size_t)(g * 64 + ed) * (EF_ + 1) + (c - NF_)];
        sm[((c >> 3) << 9) + (ed << 3) + (c & 7)] = f2bf(val);
    }
    __syncthreads();

    // ---------------- h0 GEMM: (64x160) @ WiT -> h0, write hT + keep regs ----------------
    f32x4 h0r[3][4];
    float bmv[3];
    {
        f32x4 acc[3][4];
        #pragma unroll
        for (int t = 0; t < 3; ++t)
            #pragma unroll
            for (int mt = 0; mt < 4; ++mt) acc[t][mt] = (f32x4){0.f, 0.f, 0.f, 0.f};
        #pragma unroll
        for (int ks = 0; ks < 5; ++ks) {
            bf16x8 af[4];
            #pragma unroll
            for (int mt = 0; mt < 4; ++mt)
                af[mt] = *(const bf16x8*)&sm[((ks * 4 + q) << 9) + ((mt * 16 + lm) << 3)];
            #pragma unroll
            for (int t = 0; t < 3; ++t) {
                int j = 8 * t + wave;
                if (j < NT) {
                    bf16x8 bfr = *(const bf16x8*)&WiT[(j * 16 + lm) * K0 + ks * 32 + q * 8];
                    #pragma unroll
                    for (int mt = 0; mt < 4; ++mt)
                        acc[t][mt] = __builtin_amdgcn_mfma_f32_16x16x32_bf16(af[mt], bfr, acc[t][mt], 0, 0, 0);
                }
            }
        }
        #pragma unroll
        for (int t = 0; t < 3; ++t) {
            int j = 8 * t + wave;
            int n = j * 16 + lm;
            bool ok = (j < NT) && (n < HD);
            float bv = ok ? bi[n] : 0.f;
            bmv[t] = ok ? bm[n] : 0.f;
            #pragma unroll
            for (int mt = 0; mt < 4; ++mt) {
                u64 w = 0;
                #pragma unroll
                for (int r = 0; r < 4; ++r) {
                    float hv = acc[t][mt][r] + bv;
                    hv = hv > 0.f ? hv : 0.f;
                    h0r[t][mt][r] = hv;
                    w |= ((u64)f2bf(hv)) << (16 * r);
                }
                if (ok) *(u64*)&shT[(mt * 2 + (q >> 1)) * 2560 + n * 8 + (q & 1) * 4] = w;
            }
        }
    }

    // ---------------- 3 message-passing layers, all-MFMA ----------------
    for (int layer = 0; layer < 3; ++layer) {
        __syncthreads();
        // GEMM1: m = A_e @ h  (A=sAe, B=shT) -> sm (A-layout)
        {
            bf16x8 ae[2][4];
            #pragma unroll
            for (int ks = 0; ks < 2; ++ks)
                #pragma unroll
                for (int mt = 0; mt < 4; ++mt)
                    ae[ks][mt] = *(const bf16x8*)&sAe[((ks * 4 + q) << 9) + ((mt * 16 + lm) << 3)];
            #pragma unroll
            for (int t = 0; t < 3; ++t) {
                int j = 8 * t + wave;
                if (j < NT) {
                    int col = j * 16 + lm;
                    f32x4 mac[4];
                    #pragma unroll
                    for (int mt = 0; mt < 4; ++mt) mac[mt] = (f32x4){0.f, 0.f, 0.f, 0.f};
                    #pragma unroll
                    for (int ks = 0; ks < 2; ++ks) {
                        bf16x8 bfr = *(const bf16x8*)&shT[(ks * 4 + q) * 2560 + col * 8];
                        #pragma unroll
                        for (int mt = 0; mt < 4; ++mt)
                            mac[mt] = __builtin_amdgcn_mfma_f32_16x16x32_bf16(ae[ks][mt], bfr, mac[mt], 0, 0, 0);
                    }
                    int base = ((col >> 3) << 9) + (col & 7);
                    #pragma unroll
                    for (int mt = 0; mt < 4; ++mt)
                        #pragma unroll
                        for (int r = 0; r < 4; ++r)
                            sm[base + ((mt * 16 + q * 4 + r) << 3)] = f2bf(mac[mt][r]);
                }
            }
        }
        __syncthreads();
        // GEMM2: h = relu(h0 + m @ Wm + bm) -> shT
        {
            f32x4 acc[3][4];
            #pragma unroll
            for (int t = 0; t < 3; ++t)
                #pragma unroll
                for (int mt = 0; mt < 4; ++mt) acc[t][mt] = (f32x4){0.f, 0.f, 0.f, 0.f};
            #pragma unroll
            for (int ks = 0; ks < 10; ++ks) {
                bf16x8 af[4];
                #pragma unroll
                for (int mt = 0; mt < 4; ++mt)
                    af[mt] = *(const bf16x8*)&sm[((ks * 4 + q) << 9) + ((mt * 16 + lm) << 3)];
                #pragma unroll
                for (int t = 0; t < 3; ++t) {
                    int j = 8 * t + wave;
                    if (j < NT) {
                        bf16x8 bfr = *(const bf16x8*)&WmT[(j * 16 + lm) * KH + ks * 32 + q * 8];
                        #pragma unroll
                        for (int mt = 0; mt < 4; ++mt)
                            acc[t][mt] = __builtin_amdgcn_mfma_f32_16x16x32_bf16(af[mt], bfr, acc[t][mt], 0, 0, 0);
                    }
                }
            }
            #pragma unroll
            for (int t = 0; t < 3; ++t) {
                int j = 8 * t + wave;
                int n = j * 16 + lm;
                bool ok = (j < NT) && (n < HD);
                #pragma unroll
                for (int mt = 0; mt < 4; ++mt) {
                    u64 w = 0;
                    #pragma unroll
                    for (int r = 0; r < 4; ++r) {
                        float hv = h0r[t][mt][r] + acc[t][mt][r] + bmv[t];
                        hv = hv > 0.f ? hv : 0.f;
                        w |= ((u64)f2bf(hv)) << (16 * r);
                    }
                    if (ok) *(u64*)&shT[(mt * 2 + (q >> 1)) * 2560 + n * 8 + (q & 1) * 4] = w;
                }
            }
        }
    }
    __syncthreads();

    // ---- A2 vv part + zero rest (32 x 448, A-layout R=32) into sm ----
    for (int idx = tid; idx < 32 * K2; idx += 512) {
        int n = idx / K2, c = idx - n * K2;
        float val = (c < NF_) ? vf[(size_t)(g * 32 + n) * (NF_ + 1) + c] : 0.f;
        sm[((c >> 3) << 8) + (n << 3) + (c & 7)] = f2bf(val);
    }
    __syncthreads();

    // ---- m_v = S_out @ h (A=sSo, B=shT) -> sm cols 133..432 ----
    #pragma unroll
    for (int t = 0; t < 3; ++t) {
        int j = 8 * t + wave;
        if (j < NT) {
            int hc = j * 16 + lm;
            f32x4 vacc[2];
            #pragma unroll
            for (int mt = 0; mt < 2; ++mt) vacc[mt] = (f32x4){0.f, 0.f, 0.f, 0.f};
            #pragma unroll
            for (int ks = 0; ks < 2; ++ks) {
                bf16x8 bfr = *(const bf16x8*)&shT[(ks * 4 + q) * 2560 + hc * 8];
                #pragma unroll
                for (int mt = 0; mt < 2; ++mt) {
                    bf16x8 af = *(const bf16x8*)&sSo[((ks * 4 + q) << 8) + ((mt * 16 + lm) << 3)];
                    vacc[mt] = __builtin_amdgcn_mfma_f32_16x16x32_bf16(af, bfr, vacc[mt], 0, 0, 0);
                }
            }
            if (hc < HD) {
                int cc = NF_ + hc;
                int base = ((cc >> 3) << 8) + (cc & 7);
                #pragma unroll
                for (int mt = 0; mt < 2; ++mt)
                    #pragma unroll
                    for (int r = 0; r < 4; ++r)
                        sm[base + ((mt * 16 + q * 4 + r) << 3)] = f2bf(vacc[mt][r]);
            }
        }
    }
    __syncthreads();

    // ---- h_v = relu(A2 @ Wa + ba); mean over 32 nodes -> Ar1[g][0:300] ----
    {
        f32x4 acc2[3][2];
        #pragma unroll
        for (int t = 0; t < 3; ++t)
            #pragma unroll
            for (int mt = 0; mt < 2; ++mt) acc2[t][mt] = (f32x4){0.f, 0.f, 0.f, 0.f};
        #pragma unroll
        for (int ks = 0; ks < 14; ++ks) {
            bf16x8 af[2];
            #pragma unroll
            for (int mt = 0; mt < 2; ++mt)
                af[mt] = *(const bf16x8*)&sm[((ks * 4 + q) << 8) + ((mt * 16 + lm) << 3)];
            #pragma unroll
            for (int t = 0; t < 3; ++t) {
                int j = 8 * t + wave;
                if (j < NT) {
                    bf16x8 bfr = *(const bf16x8*)&WaT[(j * 16 + lm) * K2 + ks * 32 + q * 8];
                    #pragma unroll
                    for (int mt = 0; mt < 2; ++mt)
                        acc2[t][mt] = __builtin_amdgcn_mfma_f32_16x16x32_bf16(af[mt], bfr, acc2[t][mt], 0, 0, 0);
                }
            }
        }
        #pragma unroll
        for (int t = 0; t < 3; ++t) {
            int j = 8 * t + wave;
            int n = j * 16 + lm;
            bool ok = (j < NT) && (n < HD);
            float bav = ok ? ba[n] : 0.f;
            float s = 0.f;
            #pragma unroll
            for (int mt = 0; mt < 2; ++mt)
                #pragma unroll
                for (int r = 0; r < 4; ++r) {
                    float hv = acc2[t][mt][r] + bav;
                    s += (hv > 0.f ? hv : 0.f);
                }
            s += __shfl_xor(s, 16);
            s += __shfl_xor(s, 32);
            if (ok && q == 0) Ar1[g * 512 + n] = f2bf(s * 0.03125f);
        }
    }
}

// ---------- generic LDS-free readout GEMM: C = [relu](A @ Bt^T + bias) ----------
template<int RELU, int OUTBF16>
__global__ __launch_bounds__(256, 4) void gemm_ro(
    const u16* __restrict__ A, const u16* __restrict__ Bt, const float* __restrict__ bias,
    const int KP, const int Nreal, const int outPitch, void* __restrict__ outp, const int nsteps)
{
    const int tid = threadIdx.x;
    const int wv = tid >> 6, lane = tid & 63, lm = lane & 15, q = lane >> 4;
    const int row0 = blockIdx.x * 64;
    const int col = blockIdx.y * 64 + wv * 16 + lm;
    f32x4 acc[4];
    #pragma unroll
    for (int mt = 0; mt < 4; ++mt) acc[mt] = (f32x4){0.f, 0.f, 0.f, 0.f};
    const u16* bp = Bt + col * KP + q * 8;
    const u16* ap = A + (row0 + lm) * KP + q * 8;
    for (int ks = 0; ks < nsteps; ++ks) {
        bf16x8 bfr = *(const bf16x8*)(bp + ks * 32);
        #pragma unroll
        for (int mt = 0; mt < 4; ++mt) {
            bf16x8 afr = *(const bf16x8*)(ap + mt * 16 * KP + ks * 32);
            acc[mt] = __builtin_amdgcn_mfma_f32_16x16x32_bf16(afr, bfr, acc[mt], 0, 0, 0);
        }
    }
    const float bv = (col < Nreal) ? bias[col] : 0.f;
    #pragma unroll
    for (int mt = 0; mt < 4; ++mt) {
        #pragma unroll
        for (int r = 0; r < 4; ++r) {
            int row = row0 + mt * 16 + q * 4 + r;
            float val = acc[mt][r] + bv;
            if (RELU) val = val > 0.f ? val : 0.f;
            if (OUTBF16) {
                ((u16*)outp)[row * outPitch + col] = (col < Nreal) ? f2bf(val) : (u16)0;
            } else {
                if (col < Nreal) ((float*)outp)[row * outPitch + col] = val;
            }
        }
    }
}

extern "C" void kernel_launch(void* const* d_in, const int* in_sizes, int n_in,
                              void* d_out, int out_size, void* d_ws, size_t ws_size,
                              hipStream_t stream) {
    (void)in_sizes; (void)n_in; (void)out_size; (void)ws_size;
    const float* v   = (const float*)d_in[0];
    const float* e   = (const float*)d_in[1];
    const float* glb = (const float*)d_in[2];
    const float* Wi  = (const float*)d_in[3];
    const float* bi  = (const float*)d_in[4];
    const float* Wm  = (const float*)d_in[5];
    const float* bm  = (const float*)d_in[6];
    const float* Wa  = (const float*)d_in[7];
    const float* ba  = (const float*)d_in[8];
    const float* Wr1 = (const float*)d_in[9];
    const float* br1 = (const float*)d_in[10];
    const float* Wr2 = (const float*)d_in[11];
    const float* br2 = (const float*)d_in[12];
    const float* Wr3 = (const float*)d_in[13];
    const float* br3 = (const float*)d_in[14];
    const int* src = (const int*)d_in[15];
    const int* dst = (const int*)d_in[16];

    char* ws = (char*)d_ws;
    u16* WiT  = (u16*)(ws + 0);            // 304*160*2  =   97280
    u16* WmT  = (u16*)(ws + 97280);        // 304*320*2  =  194560
    u16* WaT  = (u16*)(ws + 291840);       // 304*448*2  =  272384
    u16* Wr1T = (u16*)(ws + 564224);       // 576*512*2  =  589824
    u16* Wr2T = (u16*)(ws + 1154048);      // 384*576*2  =  442368
    u16* Wr3T = (u16*)(ws + 1596416);      //  64*384*2  =   49152
    u16* Ar1  = (u16*)(ws + 1645568);      // 4096*512*2 = 4194304
    u16* Ar2  = (u16*)(ws + 5839872);      // 4096*576*2 = 4718592
    u16* Ar3  = (u16*)(ws + 10558464);     // 4096*384*2 = 3145728

    prep_w<<<190,  256, 0, stream>>>(Wi,  WiT,  147, 300, 160, 304);
    prep_w<<<380,  256, 0, stream>>>(Wm,  WmT,  300, 300, 320, 304);
    prep_w<<<532,  256, 0, stream>>>(Wa,  WaT,  433, 300, 448, 304);
    prep_w<<<1152, 256, 0, stream>>>(Wr1, Wr1T, 500, 550, 512, 576);
    prep_w<<<864,  256, 0, stream>>>(Wr2, Wr2T, 550, 378, 576, 384);
    prep_w<<<96,   256, 0, stream>>>(Wr3, Wr3T, 378, 12,  384, 64);
    prep_glob<<<3392, 256, 0, stream>>>(glb, Ar1);

    gnn_mega<<<4096, 512, 0, stream>>>(v, e, src, dst, WiT, WmT, WaT, bi, bm, ba, Ar1);

    gemm_ro<1, 1><<<dim3(64, 9), 256, 0, stream>>>(Ar1, Wr1T, br1, 512, 550, 576, Ar2, 16);
    gemm_ro<1, 1><<<dim3(64, 6), 256, 0, stream>>>(Ar2, Wr2T, br2, 576, 378, 384, Ar3, 18);
    gemm_ro<0, 0><<<dim3(64, 1), 256, 0, stream>>>(Ar3, Wr3T, br3, 384, 12, 12, d_out, 12);
}